// Round 18
// baseline (236.434 us; speedup 1.0000x reference)
//
#include <hip/hip_runtime.h>
#include <hip/hip_bf16.h>

#define B_ 4
#define S_ 4096
#define D_ 256

typedef __attribute__((ext_vector_type(8))) short bf16x8;
typedef __attribute__((ext_vector_type(4))) short short4v;
typedef __attribute__((ext_vector_type(4))) float f32x4;

// round-to-nearest-even f32 -> bf16 bits (inputs finite)
static __device__ __forceinline__ unsigned short f2bf(float f) {
    unsigned int u = __float_as_uint(f);
    u += 0x7fffu + ((u >> 16) & 1u);
    return (unsigned short)(u >> 16);
}
static __device__ __forceinline__ float bf2f(unsigned short h) {
    return __uint_as_float(((unsigned int)h) << 16);
}
// packed f32x2 -> bf16x2 (RNE), single HW op (T12)
static __device__ __forceinline__ unsigned int cvtpk(float lo, float hi) {
    unsigned int r;
    asm("v_cvt_pk_bf16_f32 %0, %1, %2" : "=v"(r) : "v"(lo), "v"(hi));
    return r;
}

// async global -> LDS DMA, 16B/lane: LDS gets base + lane*16 (linear);
// global source is per-lane (pre-swizzled to realize swizzled LDS layouts).
static __device__ __forceinline__ void gload16(const void* g, void* l) {
    __builtin_amdgcn_global_load_lds(
        (const __attribute__((address_space(1))) unsigned int*)g,
        (__attribute__((address_space(3))) unsigned int*)l, 16, 0, 0);
}

// 16x16x16 bf16 MFMA (A/B = 4 bf16 = 2 VGPRs, C/D = 4 f32) — certified r16
#if __has_builtin(__builtin_amdgcn_mfma_f32_16x16x16bf16_1k)
#define MFMA16(a, b, c) __builtin_amdgcn_mfma_f32_16x16x16bf16_1k(a, b, c, 0, 0, 0)
#elif __has_builtin(__builtin_amdgcn_mfma_f32_16x16x16_bf16)
#define MFMA16(a, b, c) __builtin_amdgcn_mfma_f32_16x16x16_bf16(a, b, c, 0, 0, 0)
#else
static __device__ __forceinline__ f32x4 mfma16_asm(short4v a, short4v b, f32x4 c) {
    asm volatile("v_mfma_f32_16x16x16_bf16 %0, %1, %2, %0"
                 : "+v"(c) : "v"(a), "v"(b));
    return c;
}
#define MFMA16(a, b, c) mfma16_asm(a, b, c)
#endif

// counted-vmcnt barrier (T4): N loads may stay in flight across the barrier.
template<int VW>
static __device__ __forceinline__ void wait_barrier() {
    if constexpr (VW == 8)      asm volatile("s_waitcnt vmcnt(8)" ::: "memory");
    else if constexpr (VW == 4) asm volatile("s_waitcnt vmcnt(4)" ::: "memory");
    else                        asm volatile("s_waitcnt vmcnt(0)" ::: "memory");
    __builtin_amdgcn_sched_barrier(0);
    __builtin_amdgcn_s_barrier();
    __builtin_amdgcn_sched_barrier(0);
}

// ---------------------------------------------------------------------------
// Kernel 1 (certified r6-r17): QKV = X @ W^T + b, f32 in, bf16 out.
// Q,K row-major [b*S+s][256]; V transposed Vt[b][d][s]. BM=BN=BK=64.
// ---------------------------------------------------------------------------
__global__ __launch_bounds__(256) void qkv_proj(
    const float* __restrict__ X, const float* __restrict__ W,
    const float* __restrict__ bias,
    unsigned short* __restrict__ Qb, unsigned short* __restrict__ Kb,
    unsigned short* __restrict__ Vt)
{
    __shared__ __align__(16) unsigned short As[64 * 64];
    __shared__ __align__(16) unsigned short Bs[64 * 64];

    const int tid  = threadIdx.x;
    const int lane = tid & 63;
    const int wid  = tid >> 6;
    const int wm   = wid >> 1, wn = wid & 1;
    const int c    = lane & 15, q4 = lane >> 4;
    const int gm0  = blockIdx.x * 64;
    const int gn0  = blockIdx.y * 64;
    const int sr   = tid >> 2;
    const int sc   = (tid & 3) * 16;

    f32x4 acc[2][2] = {};

    for (int kt = 0; kt < 4; ++kt) {
        const int k0 = kt * 64;
        {
            const float4* ga = (const float4*)(X + (size_t)(gm0 + sr) * D_ + k0 + sc);
            const float4* gb = (const float4*)(W + (size_t)(gn0 + sr) * D_ + k0 + sc);
            float4 a0 = ga[0], a1 = ga[1], a2 = ga[2], a3 = ga[3];
            float4 b0 = gb[0], b1 = gb[1], b2 = gb[2], b3 = gb[3];
            float af[16] = {a0.x,a0.y,a0.z,a0.w, a1.x,a1.y,a1.z,a1.w,
                            a2.x,a2.y,a2.z,a2.w, a3.x,a3.y,a3.z,a3.w};
            float bf[16] = {b0.x,b0.y,b0.z,b0.w, b1.x,b1.y,b1.z,b1.w,
                            b2.x,b2.y,b2.z,b2.w, b3.x,b3.y,b3.z,b3.w};
            bf16x8 av0, av1, bv0, bv1;
            #pragma unroll
            for (int j = 0; j < 8; ++j) {
                av0[j] = (short)f2bf(af[j]);     av1[j] = (short)f2bf(af[8 + j]);
                bv0[j] = (short)f2bf(bf[j]);     bv1[j] = (short)f2bf(bf[8 + j]);
            }
            const int sw = (sr & 7) << 3;
            *(bf16x8*)&As[sr * 64 + ((sc + 0) ^ sw)] = av0;
            *(bf16x8*)&As[sr * 64 + ((sc + 8) ^ sw)] = av1;
            *(bf16x8*)&Bs[sr * 64 + ((sc + 0) ^ sw)] = bv0;
            *(bf16x8*)&Bs[sr * 64 + ((sc + 8) ^ sw)] = bv1;
        }
        __syncthreads();
        const int sw = (c & 7) << 3;
        #pragma unroll
        for (int kk = 0; kk < 64; kk += 32) {
            bf16x8 afr[2], bfr[2];
            #pragma unroll
            for (int mf = 0; mf < 2; ++mf) {
                const int row = wm * 32 + mf * 16 + c;
                afr[mf] = *(const bf16x8*)&As[row * 64 + ((kk + 8 * q4) ^ sw)];
            }
            #pragma unroll
            for (int nf = 0; nf < 2; ++nf) {
                const int row = wn * 32 + nf * 16 + c;
                bfr[nf] = *(const bf16x8*)&Bs[row * 64 + ((kk + 8 * q4) ^ sw)];
            }
            #pragma unroll
            for (int mf = 0; mf < 2; ++mf)
                #pragma unroll
                for (int nf = 0; nf < 2; ++nf)
                    acc[mf][nf] = __builtin_amdgcn_mfma_f32_16x16x32_bf16(
                        afr[mf], bfr[nf], acc[mf][nf], 0, 0, 0);
        }
        __syncthreads();
    }

    const int b  = gm0 >> 12;
    const int s0 = gm0 & 4095;
    #pragma unroll
    for (int mf = 0; mf < 2; ++mf) {
        #pragma unroll
        for (int nf = 0; nf < 2; ++nf) {
            const int e  = gn0 + wn * 32 + nf * 16 + c;
            const float bv = bias[e];
            const int srow0 = s0 + wm * 32 + mf * 16 + 4 * q4;
            if (e < 256) {
                #pragma unroll
                for (int i = 0; i < 4; ++i)
                    Qb[((size_t)b * S_ + srow0 + i) * D_ + e] =
                        f2bf(acc[mf][nf][i] + bv);
            } else if (e < 512) {
                #pragma unroll
                for (int i = 0; i < 4; ++i)
                    Kb[((size_t)b * S_ + srow0 + i) * D_ + (e - 256)] =
                        f2bf(acc[mf][nf][i] + bv);
            } else {
                short4v pv;
                #pragma unroll
                for (int i = 0; i < 4; ++i)
                    pv[i] = (short)f2bf(acc[mf][nf][i] + bv);
                *(short4v*)&Vt[((size_t)(b * D_ + (e - 512))) * S_ + srow0] = pv;
            }
        }
    }
}

// ---------------------------------------------------------------------------
// Kernel 2: flash attention, T3/T4 deep pipeline. 512 thr = 8 waves =
// 4 row-groups(16 q) x 2 key-halves, 2 waves/SIMD. Step = 16 keys/half
// (NS=128). 4 x 32KB LDS ring, 3 tiles in flight, counted vmcnt(8) at a raw
// s_barrier (never drain-0 in the main loop).
// Buffer (32KB): K_h0 [16][512B] slot^=row @0 | K_h1 @8192 |
//                V_h0 [256][32B] @16384 | V_h1 @24576.
// QK swapped 16x16x32: lane (qi,g) holds scores of q=q0+qi, keys 4g+r.
// PV swapped 16x16x16 (certified r16): P is fully IN-LANE (k=4g+j) -> zero
// P-assembly shuffles; 2 cvt_pk packs. Per-lane scalar softmax state.
// ---------------------------------------------------------------------------
__global__ __launch_bounds__(512, 2) void attn_fwd(
    const unsigned short* __restrict__ Qb, const unsigned short* __restrict__ Kb,
    const unsigned short* __restrict__ Vt, float* __restrict__ Out)
{
    __shared__ __align__(16) char smem[132096];
    // [0,131072): 4 x 32KB ring; Mbuf f32[64][2] @131072; Lbuf @131584
    // epilogue Obuf f32[64][260] aliases [0,66560)

    const int bid  = blockIdx.x;
    const int xcd  = bid & 7;
    const int tile = (xcd >> 1) * 64 + (bid >> 3) * 2 + (xcd & 1); // [0,256)
    const int gr0  = tile * 64;
    const int b    = gr0 >> 12;

    const int tid  = threadIdx.x;
    const int wid  = tid >> 6, lane = tid & 63;
    const int qi   = lane & 15, g = lane >> 4;
    const int rg   = wid & 3;             // row group (16 q)
    const int kh   = wid >> 2;            // key half (compute role)
    const int q0   = gr0 + rg * 16;
    const float C  = 0.09016844005556021f;   // log2(e)/sqrt(256)
    const float THR = 40.0f;

    // Q fragments (B operand): lane col = qi; d = m*32 + 8g + j
    bf16x8 qf[8];
    {
        const size_t qrow = (size_t)(q0 + qi) * D_ + 8 * g;
        #pragma unroll
        for (int m = 0; m < 8; ++m)
            qf[m] = *(const bf16x8*)&Qb[qrow + m * 32];
    }

    const unsigned short* Kbb = Kb + (size_t)b * S_ * D_;
    const unsigned short* Vtb = Vt + (size_t)b * D_ * S_;

    // --- DMA staging roles (4 gload16/thread/step): waves 0-3 K, 4-7 V ---
    const int isK = (wid < 4);
    const int sth = (wid >> 1) & 1;       // staged key half
    const int sub = wid & 1;              // sub-range within half
    int soff[4], doff[4];
    if (isK) {
        #pragma unroll
        for (int j = 0; j < 4; ++j) {
            const int r0 = sub * 8 + 2 * j + (lane >> 5);    // tile row 0..15
            soff[j] = (sth * 2048 + r0) * 256 + (((lane & 31) ^ r0) << 3);
            doff[j] = sth * 8192 + (sub * 8 + 2 * j) * 512;
        }
    } else {
        #pragma unroll
        for (int j = 0; j < 4; ++j) {
            const int d = sub * 128 + 32 * j + (lane >> 1);  // d row 0..255
            soff[j] = d * S_ + sth * 2048 + ((lane & 1) << 3);
            doff[j] = 16384 + sth * 8192 + (sub * 128 + 32 * j) * 32;
        }
    }
    const unsigned short* sbase = isK ? Kbb : Vtb;
    const int sstride = isK ? 16 * 256 : 16;   // elements per 16-key tile

    float* Mbuf = (float*)(smem + 131072);
    float* Lbuf = (float*)(smem + 131584);

    f32x4 o[16] = {};
    float m0 = -1.0e30f, l0 = 0.0f;

    auto ISSUE = [&](int t) {
        char* bb = smem + (size_t)(t & 3) * 32768;
        const unsigned short* sp = sbase + (size_t)t * sstride;
        #pragma unroll
        for (int j = 0; j < 4; ++j)
            gload16(sp + soff[j], bb + doff[j]);
    };

    auto COMPUTE = [&](int s) {
        const char* bb  = smem + (size_t)(s & 3) * 32768;
        const char* Ksb = bb + kh * 8192;
        const char* Vsb = bb + 16384 + kh * 8192;

        // QK^T (swapped), 2 chains of 4
        f32x4 sa = {}, sb2 = {};
        __builtin_amdgcn_s_setprio(1);
        #pragma unroll
        for (int m = 0; m < 4; ++m) {
            bf16x8 kf = *(const bf16x8*)(Ksb + qi * 512 + (((4 * m + g) ^ qi) << 4));
            sa = __builtin_amdgcn_mfma_f32_16x16x32_bf16(kf, qf[m], sa, 0, 0, 0);
        }
        #pragma unroll
        for (int m = 4; m < 8; ++m) {
            bf16x8 kf = *(const bf16x8*)(Ksb + qi * 512 + (((4 * m + g) ^ qi) << 4));
            sb2 = __builtin_amdgcn_mfma_f32_16x16x32_bf16(kf, qf[m], sb2, 0, 0, 0);
        }
        __builtin_amdgcn_s_setprio(0);
        f32x4 sc;
        #pragma unroll
        for (int r = 0; r < 4; ++r) sc[r] = sa[r] + sb2[r];

        // per-lane softmax (q = qi): 3 local max + 2 cross-group shfl
        float rmax = fmaxf(fmaxf(sc[0], sc[1]), fmaxf(sc[2], sc[3]));
        rmax = fmaxf(rmax, __shfl_xor(rmax, 16));
        rmax = fmaxf(rmax, __shfl_xor(rmax, 32));

        if (__any(rmax > m0 + THR)) {
            const float mn = fmaxf(m0, rmax);
            const float corr = exp2f((m0 - mn) * C);
            m0 = mn;
            l0 *= corr;
            #pragma unroll
            for (int dc = 0; dc < 16; ++dc)
                #pragma unroll
                for (int r = 0; r < 4; ++r) o[dc][r] *= corr;
        }

        float p8[4];
        float rsum = 0.f;
        #pragma unroll
        for (int r = 0; r < 4; ++r) {
            p8[r] = exp2f((sc[r] - m0) * C);
            rsum += p8[r];
        }
        rsum += __shfl_xor(rsum, 16);
        rsum += __shfl_xor(rsum, 32);
        l0 += rsum;

        // P fully in-lane: k = 4g + j (B-frag of 16x16x16)
        union U { unsigned int w[2]; short4v v; } u;
        u.w[0] = cvtpk(p8[0], p8[1]);
        u.w[1] = cvtpk(p8[2], p8[3]);

        // O^T += V-frag x P : 16 d-chunks
        __builtin_amdgcn_s_setprio(1);
        #pragma unroll
        for (int dc = 0; dc < 16; ++dc) {
            short4v vf = *(const short4v*)(Vsb + (dc * 16 + qi) * 32 + g * 8);
            o[dc] = MFMA16(vf, u.v, o[dc]);
        }
        __builtin_amdgcn_s_setprio(0);
    };

    // --- prologue: fill 3 tiles of the ring ---
    ISSUE(0); ISSUE(1); ISSUE(2);
    asm volatile("s_waitcnt vmcnt(8)" ::: "memory");   // tile 0 landed
    __builtin_amdgcn_sched_barrier(0);
    __builtin_amdgcn_s_barrier();
    __builtin_amdgcn_sched_barrier(0);

    const int NS = 128;
    int s = 0;
    for (; s < NS - 3; ++s) {
        ISSUE(s + 3);          // -> buffer (s+3)&3, consumed 3 barriers later
        COMPUTE(s);
        wait_barrier<8>();     // tile s+1 landed; s+2, s+3 stay in flight
    }
    COMPUTE(s); wait_barrier<4>(); ++s;   // tile NS-2 landed
    COMPUTE(s); wait_barrier<0>(); ++s;   // tile NS-1 landed
    COMPUTE(s);
    __syncthreads();

    // ---- merge across key halves (per-lane scalar state, certified) ----
    const int qidx = rg * 16 + qi;            // block-local row
    if (g == 0) Mbuf[qidx * 2 + kh] = m0;
    __syncthreads();

    {
        const float gm = fmaxf(Mbuf[qidx * 2], Mbuf[qidx * 2 + 1]);
        const float corr = exp2f((m0 - gm) * C);
        l0 *= corr;
        #pragma unroll
        for (int dc = 0; dc < 16; ++dc)
            #pragma unroll
            for (int r = 0; r < 4; ++r) o[dc][r] *= corr;
    }
    if (g == 0) Lbuf[qidx * 2 + kh] = l0;

    float* Obuf = (float*)smem;               // [64][260], aliases ring
    if (kh == 1) {
        #pragma unroll
        for (int dc = 0; dc < 16; ++dc)
            #pragma unroll
            for (int r = 0; r < 4; ++r)
                Obuf[qidx * 260 + dc * 16 + 4 * g + r] = o[dc][r];
    }
    __syncthreads();

    if (kh == 0) {
        const float inv = 1.0f / (Lbuf[qidx * 2] + Lbuf[qidx * 2 + 1]);
        #pragma unroll
        for (int dc = 0; dc < 16; ++dc)
            #pragma unroll
            for (int r = 0; r < 4; ++r) {
                const int d = dc * 16 + 4 * g + r;
                Out[(size_t)(q0 + qi) * D_ + d] =
                    (o[dc][r] + Obuf[qidx * 260 + d]) * inv;
            }
    }
}

extern "C" void kernel_launch(void* const* d_in, const int* in_sizes, int n_in,
                              void* d_out, int out_size, void* d_ws, size_t ws_size,
                              hipStream_t stream) {
    (void)out_size; (void)ws_size;
    const void *Xp = nullptr, *Wp = nullptr, *bp = nullptr;
    for (int i = 0; i < n_in; ++i) {
        if      (in_sizes[i] == B_ * S_ * D_) Xp = d_in[i];
        else if (in_sizes[i] == 3 * D_ * D_)  Wp = d_in[i];
        else if (in_sizes[i] == 3 * D_)       bp = d_in[i];
    }
    if (!Xp) Xp = d_in[0];
    if (!Wp) Wp = d_in[1];
    if (!bp) bp = d_in[2];

    float* Out = (float*)d_out;                                 // [B*S][256] f32

    unsigned short* Qb = (unsigned short*)d_ws;                 // 8 MiB
    unsigned short* Kb = Qb + (size_t)B_ * S_ * D_;             // 8 MiB
    unsigned short* Vt = Kb + (size_t)B_ * S_ * D_;             // 8 MiB
    // ws needed: 24 MiB

    dim3 pgrid(256, 12);
    qkv_proj<<<pgrid, 256, 0, stream>>>((const float*)Xp, (const float*)Wp,
                                        (const float*)bp, Qb, Kb, Vt);
    attn_fwd<<<256, 512, 0, stream>>>(Qb, Kb, Vt, Out);
}

// Round 19
// 158.234 us; speedup vs baseline: 1.4942x; 1.4942x over previous
//
#include <hip/hip_runtime.h>
#include <hip/hip_bf16.h>

#define B_ 4
#define S_ 4096
#define D_ 256

typedef __attribute__((ext_vector_type(8))) short bf16x8;
typedef __attribute__((ext_vector_type(4))) short short4v;
typedef __attribute__((ext_vector_type(4))) float f32x4;

// round-to-nearest-even f32 -> bf16 bits (inputs finite)
static __device__ __forceinline__ unsigned short f2bf(float f) {
    unsigned int u = __float_as_uint(f);
    u += 0x7fffu + ((u >> 16) & 1u);
    return (unsigned short)(u >> 16);
}
static __device__ __forceinline__ float bf2f(unsigned short h) {
    return __uint_as_float(((unsigned int)h) << 16);
}
// packed f32x2 -> bf16x2 (RNE), single HW op (T12)
static __device__ __forceinline__ unsigned int cvtpk(float lo, float hi) {
    unsigned int r;
    asm("v_cvt_pk_bf16_f32 %0, %1, %2" : "=v"(r) : "v"(lo), "v"(hi));
    return r;
}

// async global -> LDS DMA, 16B/lane: LDS gets base + lane*16 (linear);
// global source is per-lane (pre-swizzled to realize swizzled LDS layouts).
static __device__ __forceinline__ void gload16(const void* g, void* l) {
    __builtin_amdgcn_global_load_lds(
        (const __attribute__((address_space(1))) unsigned int*)g,
        (__attribute__((address_space(3))) unsigned int*)l, 16, 0, 0);
}

// ---------------------------------------------------------------------------
// Kernel 1 (certified r6-r17): QKV = X @ W^T + b, f32 in, bf16 out.
// Q,K row-major [b*S+s][256]; V transposed Vt[b][d][s]. BM=BN=BK=64.
// ---------------------------------------------------------------------------
__global__ __launch_bounds__(256) void qkv_proj(
    const float* __restrict__ X, const float* __restrict__ W,
    const float* __restrict__ bias,
    unsigned short* __restrict__ Qb, unsigned short* __restrict__ Kb,
    unsigned short* __restrict__ Vt)
{
    __shared__ __align__(16) unsigned short As[64 * 64];
    __shared__ __align__(16) unsigned short Bs[64 * 64];

    const int tid  = threadIdx.x;
    const int lane = tid & 63;
    const int wid  = tid >> 6;
    const int wm   = wid >> 1, wn = wid & 1;
    const int c    = lane & 15, q4 = lane >> 4;
    const int gm0  = blockIdx.x * 64;
    const int gn0  = blockIdx.y * 64;
    const int sr   = tid >> 2;
    const int sc   = (tid & 3) * 16;

    f32x4 acc[2][2] = {};

    for (int kt = 0; kt < 4; ++kt) {
        const int k0 = kt * 64;
        {
            const float4* ga = (const float4*)(X + (size_t)(gm0 + sr) * D_ + k0 + sc);
            const float4* gb = (const float4*)(W + (size_t)(gn0 + sr) * D_ + k0 + sc);
            float4 a0 = ga[0], a1 = ga[1], a2 = ga[2], a3 = ga[3];
            float4 b0 = gb[0], b1 = gb[1], b2 = gb[2], b3 = gb[3];
            float af[16] = {a0.x,a0.y,a0.z,a0.w, a1.x,a1.y,a1.z,a1.w,
                            a2.x,a2.y,a2.z,a2.w, a3.x,a3.y,a3.z,a3.w};
            float bf[16] = {b0.x,b0.y,b0.z,b0.w, b1.x,b1.y,b1.z,b1.w,
                            b2.x,b2.y,b2.z,b2.w, b3.x,b3.y,b3.z,b3.w};
            bf16x8 av0, av1, bv0, bv1;
            #pragma unroll
            for (int j = 0; j < 8; ++j) {
                av0[j] = (short)f2bf(af[j]);     av1[j] = (short)f2bf(af[8 + j]);
                bv0[j] = (short)f2bf(bf[j]);     bv1[j] = (short)f2bf(bf[8 + j]);
            }
            const int sw = (sr & 7) << 3;
            *(bf16x8*)&As[sr * 64 + ((sc + 0) ^ sw)] = av0;
            *(bf16x8*)&As[sr * 64 + ((sc + 8) ^ sw)] = av1;
            *(bf16x8*)&Bs[sr * 64 + ((sc + 0) ^ sw)] = bv0;
            *(bf16x8*)&Bs[sr * 64 + ((sc + 8) ^ sw)] = bv1;
        }
        __syncthreads();
        const int sw = (c & 7) << 3;
        #pragma unroll
        for (int kk = 0; kk < 64; kk += 32) {
            bf16x8 afr[2], bfr[2];
            #pragma unroll
            for (int mf = 0; mf < 2; ++mf) {
                const int row = wm * 32 + mf * 16 + c;
                afr[mf] = *(const bf16x8*)&As[row * 64 + ((kk + 8 * q4) ^ sw)];
            }
            #pragma unroll
            for (int nf = 0; nf < 2; ++nf) {
                const int row = wn * 32 + nf * 16 + c;
                bfr[nf] = *(const bf16x8*)&Bs[row * 64 + ((kk + 8 * q4) ^ sw)];
            }
            #pragma unroll
            for (int mf = 0; mf < 2; ++mf)
                #pragma unroll
                for (int nf = 0; nf < 2; ++nf)
                    acc[mf][nf] = __builtin_amdgcn_mfma_f32_16x16x32_bf16(
                        afr[mf], bfr[nf], acc[mf][nf], 0, 0, 0);
        }
        __syncthreads();
    }

    const int b  = gm0 >> 12;
    const int s0 = gm0 & 4095;
    #pragma unroll
    for (int mf = 0; mf < 2; ++mf) {
        #pragma unroll
        for (int nf = 0; nf < 2; ++nf) {
            const int e  = gn0 + wn * 32 + nf * 16 + c;
            const float bv = bias[e];
            const int srow0 = s0 + wm * 32 + mf * 16 + 4 * q4;
            if (e < 256) {
                #pragma unroll
                for (int i = 0; i < 4; ++i)
                    Qb[((size_t)b * S_ + srow0 + i) * D_ + e] =
                        f2bf(acc[mf][nf][i] + bv);
            } else if (e < 512) {
                #pragma unroll
                for (int i = 0; i < 4; ++i)
                    Kb[((size_t)b * S_ + srow0 + i) * D_ + (e - 256)] =
                        f2bf(acc[mf][nf][i] + bv);
            } else {
                short4v pv;
                #pragma unroll
                for (int i = 0; i < 4; ++i)
                    pv[i] = (short)f2bf(acc[mf][nf][i] + bv);
                *(short4v*)&Vt[((size_t)(b * D_ + (e - 512))) * S_ + srow0] = pv;
            }
        }
    }
}

// ---------------------------------------------------------------------------
// Kernel 2 (r15/r17 best, certified 137.8-138.0 us): flash attention.
// 512 threads = 8 waves = 4 row-groups(16 q) x 2 key-halves -> 2 waves/SIMD.
// QK swapped: sacc[kc] = mfma(Kfrag, Qfrag); PV swapped:
// o[dc] = mfma(Vt-frag, P^T-frag) -> per-lane scalar softmax state.
// DMA staging (global_load_lds), double-buffered 2x64KB. T5 setprio on
// MFMA clusters.
// ---------------------------------------------------------------------------
__global__ __launch_bounds__(512, 2) void attn_fwd(
    const unsigned short* __restrict__ Qb, const unsigned short* __restrict__ Kb,
    const unsigned short* __restrict__ Vt, float* __restrict__ Out)
{
    __shared__ __align__(16) char smem[132096];

    const int bid  = blockIdx.x;
    const int xcd  = bid & 7;
    const int tile = (xcd >> 1) * 64 + (bid >> 3) * 2 + (xcd & 1); // [0,256)
    const int gr0  = tile * 64;
    const int b    = gr0 >> 12;

    const int tid  = threadIdx.x;
    const int wid  = tid >> 6, lane = tid & 63;
    const int qi   = lane & 15, g = lane >> 4;
    const int rg   = wid & 3;             // row group (16 rows)
    const int kh   = wid >> 2;            // key half (compute role)
    const int q0   = gr0 + rg * 16;
    const float C  = 0.09016844005556021f;   // log2(e)/sqrt(256)
    const float THR = 40.0f;

    // Q fragments (B operand): lane col = qi; d = m*32 + 8g + j
    bf16x8 qf[8];
    {
        const size_t qrow = (size_t)(q0 + qi) * D_ + 8 * g;
        #pragma unroll
        for (int m = 0; m < 8; ++m)
            qf[m] = *(const bf16x8*)&Qb[qrow + m * 32];
    }

    const unsigned short* Kbb = Kb + (size_t)b * S_ * D_;
    const unsigned short* Vtb = Vt + (size_t)b * D_ * S_;

    // --- DMA staging roles (8 gload16/thread): waves 0-3 K, 4-7 V ---
    const int isK = (wid < 4);
    const int sth = (wid >> 1) & 1;       // staged key half
    const int sub = wid & 1;              // sub-range within half
    int soff[8];                          // per-lane element offsets (step-inv)
    int doff[8];                          // LDS byte offsets within buffer
    if (isK) {
        const int l5 = lane >> 5, i5 = lane & 31;
        #pragma unroll
        for (int j = 0; j < 8; ++j) {
            const int r0 = sub * 16 + 2 * j + l5;       // tile row 0..31
            soff[j] = (sth * 2048 + r0) * 256 + ((i5 ^ r0) << 3);
            doff[j] = sth * 16384 + (sub * 16 + 2 * j) * 512;
        }
    } else {
        #pragma unroll
        for (int j = 0; j < 8; ++j) {
            const int d = sub * 128 + 16 * j + (lane >> 2);
            soff[j] = d * S_ + sth * 2048 + ((((lane & 3) ^ ((lane >> 3) & 3))) << 3);
            doff[j] = 32768 + sth * 16384 + (sub * 128 + 16 * j) * 64;
        }
    }
    const unsigned short* sbase = isK ? Kbb : Vtb;

    float* Mbuf = (float*)(smem + 131072);
    float* Lbuf = (float*)(smem + 131584);

    f32x4 o[16] = {};
    float m0 = -1.0e30f, l0 = 0.0f;

    // --- prologue: DMA tile 0 into buffer 0 ---
    #pragma unroll
    for (int j = 0; j < 8; ++j)
        gload16(sbase + soff[j], smem + doff[j]);
    __builtin_amdgcn_s_waitcnt(0);
    __syncthreads();

    const int NS = 64;
    int p = 0;
    const int vsw = (g ^ ((qi >> 1) & 3)) << 4;   // V read swizzle (lane-const)

    for (int s = 0; s < NS; ++s) {
        // ---- issue DMA for tile s+1 into buffer p^1 (step top: max slack) ----
        if (s + 1 < NS) {
            const unsigned short* sb = sbase + (isK ? (s + 1) * 32 * 256
                                                    : (s + 1) * 32);
            const int bufo = (p ^ 1) * 65536;
            #pragma unroll
            for (int j = 0; j < 8; ++j)
                gload16(sb + soff[j], smem + bufo + doff[j]);
        }

        const char* Ksb = smem + p * 65536 + kh * 16384;
        const char* Vsb = smem + p * 65536 + 32768 + kh * 16384;

        // ---- QK^T (swapped), 2 independent chains (T5: setprio) ----
        f32x4 sacc[2] = {};
        __builtin_amdgcn_s_setprio(1);
        #pragma unroll
        for (int kc = 0; kc < 2; ++kc) {
            const int kr = kc * 16 + qi;
            const char* krow = Ksb + kr * 512;
            #pragma unroll
            for (int m = 0; m < 8; ++m) {
                bf16x8 kf = *(const bf16x8*)(krow + (((4 * m + g) ^ kr) << 4));
                sacc[kc] = __builtin_amdgcn_mfma_f32_16x16x32_bf16(
                    kf, qf[m], sacc[kc], 0, 0, 0);
            }
        }
        __builtin_amdgcn_s_setprio(0);

        // ---- per-lane softmax (q = qi): 8 local + 2 cross-group shfl ----
        float rmax = fmaxf(fmaxf(fmaxf(sacc[0][0], sacc[0][1]),
                                 fmaxf(sacc[0][2], sacc[0][3])),
                           fmaxf(fmaxf(sacc[1][0], sacc[1][1]),
                                 fmaxf(sacc[1][2], sacc[1][3])));
        rmax = fmaxf(rmax, __shfl_xor(rmax, 16));
        rmax = fmaxf(rmax, __shfl_xor(rmax, 32));

        if (__any(rmax > m0 + THR)) {
            const float mn = fmaxf(m0, rmax);
            const float corr = exp2f((m0 - mn) * C);
            m0 = mn;
            l0 *= corr;
            #pragma unroll
            for (int dc = 0; dc < 16; ++dc)
                #pragma unroll
                for (int r = 0; r < 4; ++r) o[dc][r] *= corr;
        }

        float p8[2][4];
        float rsum = 0.f;
        #pragma unroll
        for (int kc = 0; kc < 2; ++kc)
            #pragma unroll
            for (int r = 0; r < 4; ++r) {
                p8[kc][r] = exp2f((sacc[kc][r] - m0) * C);
                rsum += p8[kc][r];
            }
        rsum += __shfl_xor(rsum, 16);
        rsum += __shfl_xor(rsum, 32);
        l0 += rsum;

        // ---- pack P to bf16 pairs (HW cvt_pk) ----
        unsigned int pk0[2], pk1[2];
        pk0[0] = cvtpk(p8[0][0], p8[0][1]);  pk0[1] = cvtpk(p8[0][2], p8[0][3]);
        pk1[0] = cvtpk(p8[1][0], p8[1][1]);  pk1[1] = cvtpk(p8[1][2], p8[1][3]);

        // ---- assemble P^T B-fragment: k = 8g + j for own q ----
        const int A0 = qi + ((g & 1) << 5);   // src lane: group (g&1)*2
        const int A1 = A0 + 16;
        const unsigned int s00 = __shfl(pk0[0], A0), s01 = __shfl(pk0[1], A0);
        const unsigned int s02 = __shfl(pk0[0], A1), s03 = __shfl(pk0[1], A1);
        const unsigned int s10 = __shfl(pk1[0], A0), s11 = __shfl(pk1[1], A0);
        const unsigned int s12 = __shfl(pk1[0], A1), s13 = __shfl(pk1[1], A1);
        const bool hk = (g >> 1);             // which kc this lane needs
        union U { unsigned int w[4]; bf16x8 v; } pa;
        pa.w[0] = hk ? s10 : s00;  pa.w[1] = hk ? s11 : s01;
        pa.w[2] = hk ? s12 : s02;  pa.w[3] = hk ? s13 : s03;

        // ---- O^T += Vt-frag x P^T : 16 d-chunks (T5: setprio) ----
        __builtin_amdgcn_s_setprio(1);
        #pragma unroll
        for (int dc = 0; dc < 16; ++dc) {
            bf16x8 vf = *(const bf16x8*)(Vsb + (dc * 16 + qi) * 64 + vsw);
            o[dc] = __builtin_amdgcn_mfma_f32_16x16x32_bf16(vf, pa.v, o[dc], 0, 0, 0);
        }
        __builtin_amdgcn_s_setprio(0);

        __syncthreads();   // implicit vmcnt(0): tile s+1 DMAs complete
        p ^= 1;
    }

    // ---- merge across key halves (per-lane scalar state) ----
    const int qidx = rg * 16 + qi;            // block-local row
    if (g == 0) Mbuf[qidx * 2 + kh] = m0;
    __syncthreads();

    {
        const float gm = fmaxf(Mbuf[qidx * 2], Mbuf[qidx * 2 + 1]);
        const float corr = exp2f((m0 - gm) * C);
        l0 *= corr;
        #pragma unroll
        for (int dc = 0; dc < 16; ++dc)
            #pragma unroll
            for (int r = 0; r < 4; ++r) o[dc][r] *= corr;
    }
    if (g == 0) Lbuf[qidx * 2 + kh] = l0;

    float* Obuf = (float*)smem;               // [64][260], aliases KV buffers
    if (kh == 1) {
        #pragma unroll
        for (int dc = 0; dc < 16; ++dc)
            #pragma unroll
            for (int r = 0; r < 4; ++r)
                Obuf[qidx * 260 + dc * 16 + 4 * g + r] = o[dc][r];
    }
    __syncthreads();

    if (kh == 0) {
        const float inv = 1.0f / (Lbuf[qidx * 2] + Lbuf[qidx * 2 + 1]);
        #pragma unroll
        for (int dc = 0; dc < 16; ++dc)
            #pragma unroll
            for (int r = 0; r < 4; ++r) {
                const int d = dc * 16 + 4 * g + r;
                Out[(size_t)(q0 + qi) * D_ + d] =
                    (o[dc][r] + Obuf[qidx * 260 + d]) * inv;
            }
    }
}

extern "C" void kernel_launch(void* const* d_in, const int* in_sizes, int n_in,
                              void* d_out, int out_size, void* d_ws, size_t ws_size,
                              hipStream_t stream) {
    (void)out_size; (void)ws_size;
    const void *Xp = nullptr, *Wp = nullptr, *bp = nullptr;
    for (int i = 0; i < n_in; ++i) {
        if      (in_sizes[i] == B_ * S_ * D_) Xp = d_in[i];
        else if (in_sizes[i] == 3 * D_ * D_)  Wp = d_in[i];
        else if (in_sizes[i] == 3 * D_)       bp = d_in[i];
    }
    if (!Xp) Xp = d_in[0];
    if (!Wp) Wp = d_in[1];
    if (!bp) bp = d_in[2];

    float* Out = (float*)d_out;                                 // [B*S][256] f32

    unsigned short* Qb = (unsigned short*)d_ws;                 // 8 MiB
    unsigned short* Kb = Qb + (size_t)B_ * S_ * D_;             // 8 MiB
    unsigned short* Vt = Kb + (size_t)B_ * S_ * D_;             // 8 MiB
    // ws needed: 24 MiB

    dim3 pgrid(256, 12);
    qkv_proj<<<pgrid, 256, 0, stream>>>((const float*)Xp, (const float*)Wp,
                                        (const float*)bp, Qb, Kb, Vt);
    attn_fwd<<<256, 512, 0, stream>>>(Qb, Kb, Vt, Out);
}